// Round 4
// baseline (711.393 us; speedup 1.0000x reference)
//
#include <hip/hip_runtime.h>
#include <hip/hip_bf16.h>
#include <cstdint>
#include <cstddef>

// Problem dims (all tensors float32, per the reference file)
#define BB 8
#define SS 4096
#define DIN 256
#define DH 512
#define NCH 32
#define CHUNK 128      // NCH*CHUNK == SS

// ---------------- kernel 1: VALU f32 GEMM + bias + activation -> gate planes -
// Each block: 8 m-rows x all 2048 n. Each thread: 8 m x 8 j (n = (j&1)*256+tid,
// gate g = j>>1). W stays in ORIGINAL [k][512] layout: W[k*512+hh], consecutive
// tid -> coalesced 4B. X row tile staged in LDS; Xs reads are lane-uniform
// broadcasts.
__global__ __launch_bounds__(256) void gemm_valu(
    const float* __restrict__ X,   // pre-offset to batch group, [nb*SS][256]
    const float* __restrict__ Wi, const float* __restrict__ Wf,
    const float* __restrict__ Wo, const float* __restrict__ Wz,
    const float* __restrict__ bi, const float* __restrict__ bfv,
    const float* __restrict__ bo, const float* __restrict__ bz,
    float* __restrict__ Pi, float* __restrict__ Pf,
    float* Po /* aliases out */, float* __restrict__ Pz)
{
    __shared__ __align__(16) float Xs[8 * 256];   // 8 KB
    const int tid = threadIdx.x;
    const size_t m0 = (size_t)blockIdx.x * 8;

    {   // stage 8 rows x 256 k: each thread two float4s (8 floats)
        const int r = tid >> 5;          // 0..7
        const int c = (tid & 31) * 8;    // 0..248
        const float4* src = (const float4*)&X[(m0 + r) * DIN + c];
        float4* dst = (float4*)&Xs[r * DIN + c];
        dst[0] = src[0];
        dst[1] = src[1];
    }
    __syncthreads();

    const float* const Wg[4] = {Wi, Wf, Wo, Wz};

    float acc[8][8];   // [m][j]
#pragma unroll
    for (int m = 0; m < 8; m++)
#pragma unroll
        for (int j = 0; j < 8; j++) acc[m][j] = 0.f;

    for (int k = 0; k < DIN; k += 4) {
        float4 xv4[8];
#pragma unroll
        for (int m = 0; m < 8; m++)
            xv4[m] = *(const float4*)&Xs[m * DIN + k];
#pragma unroll
        for (int kk = 0; kk < 4; kk++) {
#pragma unroll
            for (int j = 0; j < 8; j++) {
                const int hh = (j & 1) * 256 + tid;
                const float w = Wg[j >> 1][(size_t)(k + kk) * DH + hh];
#pragma unroll
                for (int m = 0; m < 8; m++) {
                    const float xm = (kk == 0) ? xv4[m].x : (kk == 1) ? xv4[m].y
                                   : (kk == 2) ? xv4[m].z : xv4[m].w;
                    acc[m][j] = fmaf(xm, w, acc[m][j]);
                }
            }
        }
    }

    const float* const Bg[4] = {bi, bfv, bo, bz};
    float* const Pg[4] = {Pi, Pf, Po, Pz};
#pragma unroll
    for (int j = 0; j < 8; j++) {
        const int g  = j >> 1;
        const int hh = (j & 1) * 256 + tid;
        const float bsv = Bg[g][hh];
        float* plane = Pg[g];
#pragma unroll
        for (int m = 0; m < 8; m++) {
            const float v = acc[m][j] + bsv;
            float a;
            if (g == 0 || g == 1)
                a = __expf(fminf(fmaxf(v, -20.f), 0.f));   // exp(clip(v,-20,0))
            else if (g == 2)
                a = 1.f / (1.f + __expf(-v));              // sigmoid
            else
                a = tanhf(v);                               // tanh
            plane[(m0 + m) * DH + hh] = a;
        }
    }
}

// ---------------- kernel 2: per-chunk affine carry (A, Bc, Bn) ---------------
__global__ __launch_bounds__(256) void scan_carry(
    const float* __restrict__ Pi, const float* __restrict__ Pf,
    const float* __restrict__ Pz,
    float* __restrict__ Aa, float* __restrict__ Bca, float* __restrict__ Bna,
    int nb)
{
    const int h  = blockIdx.x * 256 + threadIdx.x;   // 0..511
    const int b  = blockIdx.y;                        // local batch 0..nb-1
    const int ch = blockIdx.z;
    const size_t base = ((size_t)(b * SS + ch * CHUNK)) * DH + h;
    const float* gi = Pi + base;
    const float* gf = Pf + base;
    const float* gz = Pz + base;

    float A = 1.f, Bc = 0.f, Bn = 0.f;
#pragma unroll 8
    for (int s = 0; s < CHUNK; s++) {
        const size_t o = (size_t)s * DH;
        const float f  = gf[o];
        const float iv = gi[o];
        const float zv = gz[o];
        Bc = fmaf(f, Bc, iv * zv);
        Bn = fmaf(f, Bn, iv);
        A *= f;
    }
    const int cidx = (ch * nb + b) * DH + h;
    Aa[cidx] = A; Bca[cidx] = Bc; Bna[cidx] = Bn;
}

// ---------------- kernel 3: sequential scan over chunk carries ---------------
__global__ __launch_bounds__(256) void scan_chunks(
    const float* __restrict__ Aa, const float* __restrict__ Bca,
    const float* __restrict__ Bna,
    float* __restrict__ Cs, float* __restrict__ Ns, int nb)
{
    const int t = blockIdx.x * 256 + threadIdx.x;   // (b,h) chain, 0..nb*512-1
    float c = 0.f, n = 1.f;
#pragma unroll
    for (int ch = 0; ch < NCH; ch++) {
        const int cidx = ch * (nb * DH) + t;
        Cs[cidx] = c; Ns[cidx] = n;                 // state BEFORE chunk ch
        const float A = Aa[cidx];
        c = fmaf(A, c, Bca[cidx]);
        n = fmaf(A, n, Bna[cidx]);
    }
}

// ---------------- kernel 4: replay chunk with true init, emit h --------------
// Po aliases out; each thread reads go[o] strictly before writing op[o].
__global__ __launch_bounds__(256) void scan_emit(
    const float* Pi, const float* Pf, const float* Po, const float* Pz,
    const float* __restrict__ Cs, const float* __restrict__ Ns,
    float* out, int nb)
{
    const int h  = blockIdx.x * 256 + threadIdx.x;
    const int b  = blockIdx.y;
    const int ch = blockIdx.z;
    const size_t base = ((size_t)(b * SS + ch * CHUNK)) * DH + h;
    const float* gi = Pi + base;
    const float* gf = Pf + base;
    const float* go = Po + base;
    const float* gz = Pz + base;
    float* op = out + base;

    const int cidx = (ch * nb + b) * DH + h;
    float c = Cs[cidx], n = Ns[cidx];
#pragma unroll 4
    for (int s = 0; s < CHUNK; s++) {
        const size_t o = (size_t)s * DH;
        const float f  = gf[o];
        const float iv = gi[o];
        const float ov = go[o];   // read o BEFORE overwriting with h
        const float zv = gz[o];
        c = fmaf(f, c, iv * zv);
        n = fmaf(f, n, iv);
        op[o] = ov * (c / (n + 1e-6f));
    }
}

// ---------------- launch -----------------------------------------------------
extern "C" void kernel_launch(void* const* d_in, const int* in_sizes, int n_in,
                              void* d_out, int out_size, void* d_ws, size_t ws_size,
                              hipStream_t stream)
{
    const float* x   = (const float*)d_in[0];
    const float* Wi  = (const float*)d_in[1];
    const float* bi  = (const float*)d_in[2];
    const float* Wf  = (const float*)d_in[3];
    const float* bfv = (const float*)d_in[4];
    const float* Wo  = (const float*)d_in[5];
    const float* bo  = (const float*)d_in[6];
    const float* Wz  = (const float*)d_in[7];
    const float* bz  = (const float*)d_in[8];
    float* out = (float*)d_out;

    // ws-adaptive: nb batches per pass; footprint(nb) ~= 25.2 MB * nb
    int nb = BB;
    while (nb > 1) {
        size_t need = 3 * (size_t)nb * SS * DH * 4      // Pi, Pf, Pz planes
                    + 5 * (size_t)NCH * nb * DH * 4;    // Aa,Bca,Bna,Cs,Ns
        if (need <= ws_size) break;
        nb >>= 1;
    }

    const size_t plane = (size_t)nb * SS * DH;   // elements per plane
    float* Pi = (float*)d_ws;
    float* Pf = Pi + plane;
    float* Pz = Pf + plane;
    float* Aa  = Pz + plane;
    float* Bca = Aa  + (size_t)NCH * nb * DH;
    float* Bna = Bca + (size_t)NCH * nb * DH;
    float* Cs  = Bna + (size_t)NCH * nb * DH;
    float* Ns  = Cs  + (size_t)NCH * nb * DH;

    for (int b0 = 0; b0 < BB; b0 += nb) {
        const float* Xb = x   + (size_t)b0 * SS * DIN;
        float*       Ob = out + (size_t)b0 * SS * DH;   // o-plane lives here
        gemm_valu<<<nb * SS / 8, 256, 0, stream>>>(
            Xb, Wi, Wf, Wo, Wz, bi, bfv, bo, bz, Pi, Pf, Ob, Pz);
        scan_carry<<<dim3(2, nb, NCH), 256, 0, stream>>>(
            Pi, Pf, Pz, Aa, Bca, Bna, nb);
        scan_chunks<<<2 * nb, 256, 0, stream>>>(Aa, Bca, Bna, Cs, Ns, nb);
        scan_emit<<<dim3(2, nb, NCH), 256, 0, stream>>>(
            Pi, Pf, Ob, Pz, Cs, Ns, Ob, nb);
    }
}

// Round 5
// 262.028 us; speedup vs baseline: 2.7150x; 2.7150x over previous
//
#include <hip/hip_runtime.h>
#include <hip/hip_bf16.h>
#include <cstdint>
#include <cstddef>

typedef __hip_bfloat16 bf16;
typedef __attribute__((ext_vector_type(8))) short short8;
typedef __attribute__((ext_vector_type(4))) short short4v;
typedef __attribute__((ext_vector_type(4))) float floatx4;

// Problem dims (all tensors float32; gates staged bf16)
#define BB 8
#define SS 4096
#define DIN 256
#define DH 512
#define NCH 64
#define CHUNK 64       // NCH*CHUNK == SS

__device__ __forceinline__ float b2f(bf16 v) { return __bfloat162float(v); }

// ---------------- kernel 0a: convert x tile (f32) -> Xb (bf16) ---------------
__global__ __launch_bounds__(256) void convert_x(
    const float* __restrict__ X, bf16* __restrict__ Xb)
{
    const int idx = blockIdx.x * 256 + threadIdx.x;   // 4 elements per thread
    float4 v = ((const float4*)X)[idx];
    bf16 o[4] = {__float2bfloat16(v.x), __float2bfloat16(v.y),
                 __float2bfloat16(v.z), __float2bfloat16(v.w)};
    ((short4v*)Xb)[idx] = *(const short4v*)o;
}

// ---------------- kernel 0b: W (f32 [256][512] x4) -> Wt (bf16 [2048][256]) --
// Wt[(g*512+h)][k] = (bf16) W_g[k*512 + h]
__global__ __launch_bounds__(256) void transpose_w(
    const float* __restrict__ Wi, const float* __restrict__ Wf,
    const float* __restrict__ Wo, const float* __restrict__ Wz,
    bf16* __restrict__ Wt)
{
    int o  = blockIdx.x * 256 + threadIdx.x;   // 0..524287
    int nf = o >> 8;                           // 0..2047
    int k  = o & 255;
    int g  = nf >> 9;
    int hh = nf & 511;
    const float* W = (g == 0) ? Wi : (g == 1) ? Wf : (g == 2) ? Wo : Wz;
    Wt[o] = __float2bfloat16(W[(size_t)k * DH + hh]);
}

// ---------------- kernel 1: MFMA GEMM + bias + activation -> gate planes -----
// m97-verified structure: 128x128 tile, BK=32, global_load_lds width 16,
// mfma_f32_16x16x32_bf16; A=Xb [M][256], B=Wt [2048][256] (B^T layout).
// Pi,Pf,Pz are bf16 planes in ws; Po is f32 and aliases d_out.
__device__ __forceinline__ void load16_lds(const bf16* g, short* l)
{
    __builtin_amdgcn_global_load_lds(
        (const __attribute__((address_space(1))) unsigned int*)g,
        (__attribute__((address_space(3))) unsigned int*)l,
        16, 0, 0);
}

__global__ __launch_bounds__(256) void gemm_mfma(
    const bf16* __restrict__ Xb, const bf16* __restrict__ Wt,
    const float* __restrict__ bi, const float* __restrict__ bfv,
    const float* __restrict__ bo, const float* __restrict__ bz,
    bf16* __restrict__ Pi, bf16* __restrict__ Pf,
    float* Po /* aliases out */, bf16* __restrict__ Pz)
{
    __shared__ __align__(16) short As[128 * 32];   // 8 KB
    __shared__ __align__(16) short Bs[128 * 32];   // 8 KB

    const int tid  = threadIdx.x;
    const int m0   = blockIdx.x * 128;
    const int n0   = blockIdx.y * 128;
    const int wave = tid >> 6, lane = tid & 63;
    const int wm   = (wave >> 1) * 64, wn = (wave & 1) * 64;
    const int l15  = lane & 15;      // A/B row within 16; C col
    const int q    = lane >> 4;      // A/B k-chunk; C row-quad

    floatx4 acc[4][4];
#pragma unroll
    for (int i = 0; i < 4; i++)
#pragma unroll
        for (int j = 0; j < 4; j++) acc[i][j] = (floatx4){0.f, 0.f, 0.f, 0.f};

    const int r_ld = tid >> 2;   // 0..63
    const int c_ld = tid & 3;    // 0..3 (8-elem = 16B chunk)
    const bf16* agp0 = Xb + (size_t)(m0 + r_ld) * DIN + c_ld * 8;
    const bf16* agp1 = Xb + (size_t)(m0 + 64 + r_ld) * DIN + c_ld * 8;
    const bf16* bgp0 = Wt + (size_t)(n0 + r_ld) * DIN + c_ld * 8;
    const bf16* bgp1 = Wt + (size_t)(n0 + 64 + r_ld) * DIN + c_ld * 8;

    for (int k0 = 0; k0 < DIN; k0 += 32) {
        load16_lds(agp0 + k0, &As[tid * 8]);
        load16_lds(agp1 + k0, &As[2048 + tid * 8]);
        load16_lds(bgp0 + k0, &Bs[tid * 8]);
        load16_lds(bgp1 + k0, &Bs[2048 + tid * 8]);
        __syncthreads();   // drains DMA (vmcnt) before frag reads

        short8 af[4], bfr[4];
#pragma unroll
        for (int ti = 0; ti < 4; ti++)
            af[ti] = *(const short8*)&As[(wm + ti * 16 + l15) * 32 + q * 8];
#pragma unroll
        for (int tj = 0; tj < 4; tj++)
            bfr[tj] = *(const short8*)&Bs[(wn + tj * 16 + l15) * 32 + q * 8];
#pragma unroll
        for (int ti = 0; ti < 4; ti++)
#pragma unroll
            for (int tj = 0; tj < 4; tj++)
                acc[ti][tj] = __builtin_amdgcn_mfma_f32_16x16x32_bf16(
                    af[ti], bfr[tj], acc[ti][tj], 0, 0, 0);
        __syncthreads();   // protect LDS reuse next iteration
    }

    // epilogue: whole block inside one gate (BN=128 divides 512)
    const int g = n0 >> 9;   // uniform per block
    const float* bias = (g == 0) ? bi : (g == 1) ? bfv : (g == 2) ? bo : bz;
    bf16* pb = (g == 0) ? Pi : (g == 1) ? Pf : Pz;

#pragma unroll
    for (int ti = 0; ti < 4; ti++) {
        const int mrow = m0 + wm + ti * 16 + q * 4;   // C row = q*4 + r
#pragma unroll
        for (int tj = 0; tj < 4; tj++) {
            const int n  = n0 + wn + tj * 16 + l15;   // C col
            const int hh = n & 511;
            const float bsv = bias[hh];
#pragma unroll
            for (int r = 0; r < 4; r++) {
                const float v = acc[ti][tj][r] + bsv;
                float a;
                if (g == 0 || g == 1) {
                    a = __expf(fminf(fmaxf(v, -20.f), 0.f));  // exp(clip(v,-20,0))
                } else if (g == 2) {
                    float vc = fminf(fmaxf(v, -30.f), 30.f);  // NaN-laundering clamp
                    a = 1.f / (1.f + __expf(-vc));
                } else {
                    float vc = fminf(fmaxf(v, -30.f), 30.f);
                    a = tanhf(vc);
                }
                const size_t oidx = (size_t)(mrow + r) * DH + hh;
                if (g == 2) Po[oidx] = a;
                else        pb[oidx] = __float2bfloat16(a);
            }
        }
    }
}

// ---------------- kernel 2: per-chunk affine carry (A, Bc, Bn) ---------------
__global__ __launch_bounds__(256) void scan_carry(
    const bf16* __restrict__ Pi, const bf16* __restrict__ Pf,
    const bf16* __restrict__ Pz,
    float* __restrict__ Aa, float* __restrict__ Bca, float* __restrict__ Bna,
    int nb)
{
    const int h  = blockIdx.x * 256 + threadIdx.x;   // 0..511
    const int b  = blockIdx.y;
    const int ch = blockIdx.z;
    const size_t base = ((size_t)(b * SS + ch * CHUNK)) * DH + h;
    const bf16* gi = Pi + base;
    const bf16* gf = Pf + base;
    const bf16* gz = Pz + base;

    float A = 1.f, Bc = 0.f, Bn = 0.f;
#pragma unroll 8
    for (int s = 0; s < CHUNK; s++) {
        const size_t o = (size_t)s * DH;
        const float f  = b2f(gf[o]);
        const float iv = b2f(gi[o]);
        const float zv = b2f(gz[o]);
        Bc = fmaf(f, Bc, iv * zv);
        Bn = fmaf(f, Bn, iv);
        A *= f;
    }
    const int cidx = (ch * nb + b) * DH + h;
    Aa[cidx] = A; Bca[cidx] = Bc; Bna[cidx] = Bn;
}

// ---------------- kernel 3: sequential scan over chunk carries ---------------
__global__ __launch_bounds__(256) void scan_chunks(
    const float* __restrict__ Aa, const float* __restrict__ Bca,
    const float* __restrict__ Bna,
    float* __restrict__ Cs, float* __restrict__ Ns, int nb)
{
    const int t = blockIdx.x * 256 + threadIdx.x;   // b*512+h, 0..nb*512-1
    float c = 0.f, n = 1.f;
#pragma unroll
    for (int ch = 0; ch < NCH; ch++) {
        const int cidx = ch * (nb * DH) + t;
        Cs[cidx] = c; Ns[cidx] = n;                 // state BEFORE chunk ch
        const float A = Aa[cidx];
        c = fmaf(A, c, Bca[cidx]);
        n = fmaf(A, n, Bna[cidx]);
    }
}

// ---------------- kernel 4: replay chunk with true init, emit h --------------
// Po (f32) aliases out; each thread reads go strictly before writing op.
__global__ __launch_bounds__(256) void scan_emit(
    const bf16* __restrict__ Pi, const bf16* __restrict__ Pf,
    const float* Po, const bf16* __restrict__ Pz,
    const float* __restrict__ Cs, const float* __restrict__ Ns,
    float* out, int nb)
{
    const int h  = blockIdx.x * 256 + threadIdx.x;
    const int b  = blockIdx.y;
    const int ch = blockIdx.z;
    const size_t base = ((size_t)(b * SS + ch * CHUNK)) * DH + h;
    const bf16* gi = Pi + base;
    const bf16* gf = Pf + base;
    const float* go = Po + base;
    const bf16* gz = Pz + base;
    float* op = out + base;

    const int cidx = (ch * nb + b) * DH + h;
    float c = Cs[cidx], n = Ns[cidx];
#pragma unroll 4
    for (int s = 0; s < CHUNK; s++) {
        const size_t o = (size_t)s * DH;
        const float f  = b2f(gf[o]);
        const float iv = b2f(gi[o]);
        const float ov = go[o];        // read o BEFORE overwriting with h
        const float zv = b2f(gz[o]);
        c = fmaf(f, c, iv * zv);
        n = fmaf(f, n, iv);
        op[o] = ov * (c / (n + 1e-6f));
    }
}

// ---------------- launch -----------------------------------------------------
extern "C" void kernel_launch(void* const* d_in, const int* in_sizes, int n_in,
                              void* d_out, int out_size, void* d_ws, size_t ws_size,
                              hipStream_t stream)
{
    const float* x   = (const float*)d_in[0];
    const float* Wi  = (const float*)d_in[1];
    const float* bi  = (const float*)d_in[2];
    const float* Wf  = (const float*)d_in[3];
    const float* bfv = (const float*)d_in[4];
    const float* Wo  = (const float*)d_in[5];
    const float* bo  = (const float*)d_in[6];
    const float* Wz  = (const float*)d_in[7];
    const float* bz  = (const float*)d_in[8];
    float* out = (float*)d_out;

    // ws-adaptive: nb batches per pass.
    // footprint(nb) = Wt 1MB + Xb 2MB*nb + 3 bf16 planes 12MB*nb + scan 0.66MB*nb
    int nb = BB;
    while (nb > 1) {
        size_t need = (1u << 20)
                    + (size_t)nb * SS * DIN * 2
                    + 3 * (size_t)nb * SS * DH * 2
                    + 5 * (size_t)NCH * nb * DH * 4;
        if (need <= ws_size) break;
        nb >>= 1;
    }

    const size_t plane = (size_t)nb * SS * DH;   // elements per gate plane
    bf16* Wt = (bf16*)d_ws;                      // 1 MB
    bf16* Xb = (bf16*)((char*)d_ws + (1u << 20));
    bf16* Pi = Xb + (size_t)nb * SS * DIN;
    bf16* Pf = Pi + plane;
    bf16* Pz = Pf + plane;
    float* Aa  = (float*)(Pz + plane);
    float* Bca = Aa  + (size_t)NCH * nb * DH;
    float* Bna = Bca + (size_t)NCH * nb * DH;
    float* Cs  = Bna + (size_t)NCH * nb * DH;
    float* Ns  = Cs  + (size_t)NCH * nb * DH;

    transpose_w<<<2048, 256, 0, stream>>>(Wi, Wf, Wo, Wz, Wt);

    for (int b0 = 0; b0 < BB; b0 += nb) {
        const float* Xsrc = x   + (size_t)b0 * SS * DIN;
        float*       Ob   = out + (size_t)b0 * SS * DH;   // o-plane lives here
        convert_x<<<nb * 1024, 256, 0, stream>>>(Xsrc, Xb);
        gemm_mfma<<<dim3(nb * SS / 128, 16), 256, 0, stream>>>(
            Xb, Wt, bi, bfv, bo, bz, Pi, Pf, Ob, Pz);
        scan_carry<<<dim3(2, nb, NCH), 256, 0, stream>>>(
            Pi, Pf, Pz, Aa, Bca, Bna, nb);
        scan_chunks<<<2 * nb, 256, 0, stream>>>(Aa, Bca, Bna, Cs, Ns, nb);
        scan_emit<<<dim3(2, nb, NCH), 256, 0, stream>>>(
            Pi, Pf, Ob, Pz, Cs, Ns, Ob, nb);
    }
}

// Round 6
// 244.588 us; speedup vs baseline: 2.9085x; 1.0713x over previous
//
#include <hip/hip_runtime.h>
#include <hip/hip_bf16.h>
#include <cstdint>
#include <cstddef>

typedef __hip_bfloat16 bf16;
typedef __attribute__((ext_vector_type(8))) short short8;
typedef __attribute__((ext_vector_type(4))) short short4v;
typedef __attribute__((ext_vector_type(4))) float floatx4;

// Problem dims (all tensors float32; gates staged bf16)
#define BB 8
#define SS 4096
#define DIN 256
#define DH 512
#define NCH 128
#define CHUNK 32       // NCH*CHUNK == SS

__device__ __forceinline__ float b2f(bf16 v) { return __bfloat162float(v); }
__device__ __forceinline__ float sh2f(short v) {
    unsigned int u = ((unsigned int)(unsigned short)v) << 16;
    float f; __builtin_memcpy(&f, &u, 4); return f;
}
__device__ __forceinline__ float frcp(float x) { return __builtin_amdgcn_rcpf(x); }

// ---------------- kernel 0a: convert x tile (f32) -> Xb (bf16) ---------------
__global__ __launch_bounds__(256) void convert_x(
    const float* __restrict__ X, bf16* __restrict__ Xb)
{
    const int idx = blockIdx.x * 256 + threadIdx.x;   // 4 elements per thread
    float4 v = ((const float4*)X)[idx];
    bf16 o[4] = {__float2bfloat16(v.x), __float2bfloat16(v.y),
                 __float2bfloat16(v.z), __float2bfloat16(v.w)};
    ((short4v*)Xb)[idx] = *(const short4v*)o;
}

// ---------------- kernel 0b: W (f32 [256][512] x4) -> Wt (bf16 [2048][256]) --
__global__ __launch_bounds__(256) void transpose_w(
    const float* __restrict__ Wi, const float* __restrict__ Wf,
    const float* __restrict__ Wo, const float* __restrict__ Wz,
    bf16* __restrict__ Wt)
{
    int o  = blockIdx.x * 256 + threadIdx.x;   // 0..524287
    int nf = o >> 8;
    int k  = o & 255;
    int g  = nf >> 9;
    int hh = nf & 511;
    const float* W = (g == 0) ? Wi : (g == 1) ? Wf : (g == 2) ? Wo : Wz;
    Wt[o] = __float2bfloat16(W[(size_t)k * DH + hh]);
}

// ---------------- kernel 1: MFMA GEMM + bias + fast activation ---------------
__device__ __forceinline__ void load16_lds(const bf16* g, short* l)
{
    __builtin_amdgcn_global_load_lds(
        (const __attribute__((address_space(1))) unsigned int*)g,
        (__attribute__((address_space(3))) unsigned int*)l,
        16, 0, 0);
}

__global__ __launch_bounds__(256) void gemm_mfma(
    const bf16* __restrict__ Xb, const bf16* __restrict__ Wt,
    const float* __restrict__ bi, const float* __restrict__ bfv,
    const float* __restrict__ bo, const float* __restrict__ bz,
    bf16* __restrict__ Pi, bf16* __restrict__ Pf,
    bf16* __restrict__ Po, bf16* __restrict__ Pz)
{
    __shared__ __align__(16) short As[128 * 32];
    __shared__ __align__(16) short Bs[128 * 32];

    const int tid  = threadIdx.x;
    const int m0   = blockIdx.x * 128;
    const int n0   = blockIdx.y * 128;
    const int wave = tid >> 6, lane = tid & 63;
    const int wm   = (wave >> 1) * 64, wn = (wave & 1) * 64;
    const int l15  = lane & 15;
    const int q    = lane >> 4;

    floatx4 acc[4][4];
#pragma unroll
    for (int i = 0; i < 4; i++)
#pragma unroll
        for (int j = 0; j < 4; j++) acc[i][j] = (floatx4){0.f, 0.f, 0.f, 0.f};

    const int r_ld = tid >> 2;
    const int c_ld = tid & 3;
    const bf16* agp0 = Xb + (size_t)(m0 + r_ld) * DIN + c_ld * 8;
    const bf16* agp1 = Xb + (size_t)(m0 + 64 + r_ld) * DIN + c_ld * 8;
    const bf16* bgp0 = Wt + (size_t)(n0 + r_ld) * DIN + c_ld * 8;
    const bf16* bgp1 = Wt + (size_t)(n0 + 64 + r_ld) * DIN + c_ld * 8;

    for (int k0 = 0; k0 < DIN; k0 += 32) {
        load16_lds(agp0 + k0, &As[tid * 8]);
        load16_lds(agp1 + k0, &As[2048 + tid * 8]);
        load16_lds(bgp0 + k0, &Bs[tid * 8]);
        load16_lds(bgp1 + k0, &Bs[2048 + tid * 8]);
        __syncthreads();

        short8 af[4], bfr[4];
#pragma unroll
        for (int ti = 0; ti < 4; ti++)
            af[ti] = *(const short8*)&As[(wm + ti * 16 + l15) * 32 + q * 8];
#pragma unroll
        for (int tj = 0; tj < 4; tj++)
            bfr[tj] = *(const short8*)&Bs[(wn + tj * 16 + l15) * 32 + q * 8];
#pragma unroll
        for (int ti = 0; ti < 4; ti++)
#pragma unroll
            for (int tj = 0; tj < 4; tj++)
                acc[ti][tj] = __builtin_amdgcn_mfma_f32_16x16x32_bf16(
                    af[ti], bfr[tj], acc[ti][tj], 0, 0, 0);
        __syncthreads();
    }

    const int g = n0 >> 9;   // uniform per block
    const float* bias = (g == 0) ? bi : (g == 1) ? bfv : (g == 2) ? bo : bz;
    bf16* pb = (g == 0) ? Pi : (g == 1) ? Pf : (g == 2) ? Po : Pz;

#pragma unroll
    for (int ti = 0; ti < 4; ti++) {
        const int mrow = m0 + wm + ti * 16 + q * 4;
#pragma unroll
        for (int tj = 0; tj < 4; tj++) {
            const int hh = (n0 + wn + tj * 16 + l15) & 511;
            const float bsv = bias[hh];
#pragma unroll
            for (int r = 0; r < 4; r++) {
                const float v = acc[ti][tj][r] + bsv;
                float a;
                if (g == 0 || g == 1) {
                    a = __expf(fminf(fmaxf(v, -20.f), 0.f));     // exp(clip)
                } else if (g == 2) {
                    a = frcp(1.f + __expf(-v));                  // sigmoid (safe at +-inf)
                } else {
                    a = 1.f - 2.f * frcp(__expf(2.f * v) + 1.f); // tanh (safe at +-inf)
                }
                pb[(size_t)(mrow + r) * DH + hh] = __float2bfloat16(a);
            }
        }
    }
}

// ---------------- kernel 2: per-chunk affine carry, 8 chains/thread ----------
// grid (NCH/4, nb), block 256: sub-chunk = tid>>6, h-group = (tid&63)*8
__global__ __launch_bounds__(256) void scan_carry(
    const bf16* __restrict__ Pi, const bf16* __restrict__ Pf,
    const bf16* __restrict__ Pz,
    float* __restrict__ Aa, float* __restrict__ Bca, float* __restrict__ Bna,
    int nb)
{
    const int tid = threadIdx.x;
    const int ch  = blockIdx.x * 4 + (tid >> 6);
    const int b   = blockIdx.y;
    const int hg  = (tid & 63) * 8;
    const size_t base = ((size_t)(b * SS + ch * CHUNK)) * DH + hg;

    float A[8], Bc[8], Bn[8];
#pragma unroll
    for (int j = 0; j < 8; j++) { A[j] = 1.f; Bc[j] = 0.f; Bn[j] = 0.f; }

#pragma unroll 4
    for (int s = 0; s < CHUNK; s++) {
        const size_t o = base + (size_t)s * DH;
        short8 i8 = *(const short8*)(Pi + o);
        short8 f8 = *(const short8*)(Pf + o);
        short8 z8 = *(const short8*)(Pz + o);
#pragma unroll
        for (int j = 0; j < 8; j++) {
            const float f  = sh2f(f8[j]);
            const float iv = sh2f(i8[j]);
            const float zv = sh2f(z8[j]);
            Bc[j] = fmaf(f, Bc[j], iv * zv);
            Bn[j] = fmaf(f, Bn[j], iv);
            A[j] *= f;
        }
    }
    const size_t cidx = (size_t)(ch * nb + b) * DH + hg;
#pragma unroll
    for (int j = 0; j < 2; j++) {
        *(floatx4*)(Aa  + cidx + j * 4) = *(floatx4*)&A[j * 4];
        *(floatx4*)(Bca + cidx + j * 4) = *(floatx4*)&Bc[j * 4];
        *(floatx4*)(Bna + cidx + j * 4) = *(floatx4*)&Bn[j * 4];
    }
}

// ---------------- kernel 3: sequential scan over chunk carries ---------------
__global__ __launch_bounds__(256) void scan_chunks(
    const float* __restrict__ Aa, const float* __restrict__ Bca,
    const float* __restrict__ Bna,
    float* __restrict__ Cs, float* __restrict__ Ns, int nb)
{
    const int t = blockIdx.x * 256 + threadIdx.x;   // b*512+h chain
    float c = 0.f, n = 1.f;
    for (int ch = 0; ch < NCH; ch++) {
        const size_t cidx = (size_t)ch * (nb * DH) + t;
        Cs[cidx] = c; Ns[cidx] = n;                 // state BEFORE chunk ch
        const float A = Aa[cidx];
        c = fmaf(A, c, Bca[cidx]);
        n = fmaf(A, n, Bna[cidx]);
    }
}

// ---------------- kernel 4: replay chunk with true init, emit h (f32) --------
__global__ __launch_bounds__(256) void scan_emit(
    const bf16* __restrict__ Pi, const bf16* __restrict__ Pf,
    const bf16* __restrict__ Po, const bf16* __restrict__ Pz,
    const float* __restrict__ Cs, const float* __restrict__ Ns,
    float* __restrict__ out, int nb)
{
    const int tid = threadIdx.x;
    const int ch  = blockIdx.x * 4 + (tid >> 6);
    const int b   = blockIdx.y;
    const int hg  = (tid & 63) * 8;
    const size_t base = ((size_t)(b * SS + ch * CHUNK)) * DH + hg;
    const size_t cidx = (size_t)(ch * nb + b) * DH + hg;

    float c[8], n[8];
#pragma unroll
    for (int j = 0; j < 2; j++) {
        *(floatx4*)&c[j * 4] = *(const floatx4*)(Cs + cidx + j * 4);
        *(floatx4*)&n[j * 4] = *(const floatx4*)(Ns + cidx + j * 4);
    }

#pragma unroll 4
    for (int s = 0; s < CHUNK; s++) {
        const size_t o = base + (size_t)s * DH;
        short8 i8 = *(const short8*)(Pi + o);
        short8 f8 = *(const short8*)(Pf + o);
        short8 o8 = *(const short8*)(Po + o);
        short8 z8 = *(const short8*)(Pz + o);
        float h[8];
#pragma unroll
        for (int j = 0; j < 8; j++) {
            const float f  = sh2f(f8[j]);
            const float iv = sh2f(i8[j]);
            const float ov = sh2f(o8[j]);
            const float zv = sh2f(z8[j]);
            c[j] = fmaf(f, c[j], iv * zv);
            n[j] = fmaf(f, n[j], iv);
            h[j] = ov * c[j] * frcp(n[j] + 1e-6f);
        }
        *(floatx4*)(out + o)     = *(floatx4*)&h[0];
        *(floatx4*)(out + o + 4) = *(floatx4*)&h[4];
    }
}

// ---------------- launch -----------------------------------------------------
extern "C" void kernel_launch(void* const* d_in, const int* in_sizes, int n_in,
                              void* d_out, int out_size, void* d_ws, size_t ws_size,
                              hipStream_t stream)
{
    const float* x   = (const float*)d_in[0];
    const float* Wi  = (const float*)d_in[1];
    const float* bi  = (const float*)d_in[2];
    const float* Wf  = (const float*)d_in[3];
    const float* bfv = (const float*)d_in[4];
    const float* Wo  = (const float*)d_in[5];
    const float* bo  = (const float*)d_in[6];
    const float* Wz  = (const float*)d_in[7];
    const float* bz  = (const float*)d_in[8];
    float* out = (float*)d_out;

    // ws-adaptive: nb batches per pass.
    int nb = BB;
    while (nb > 1) {
        size_t need = (1u << 20)                         // Wt
                    + (size_t)nb * SS * DIN * 2          // Xb
                    + 4 * (size_t)nb * SS * DH * 2       // Pi,Pf,Po,Pz
                    + 5 * (size_t)NCH * nb * DH * 4;     // scan arrays
        if (need <= ws_size) break;
        nb >>= 1;
    }

    const size_t plane = (size_t)nb * SS * DH;
    bf16* Wt = (bf16*)d_ws;
    bf16* Xb = (bf16*)((char*)d_ws + (1u << 20));
    bf16* Pi = Xb + (size_t)nb * SS * DIN;
    bf16* Pf = Pi + plane;
    bf16* Po = Pf + plane;
    bf16* Pz = Po + plane;
    float* Aa  = (float*)(Pz + plane);
    float* Bca = Aa  + (size_t)NCH * nb * DH;
    float* Bna = Bca + (size_t)NCH * nb * DH;
    float* Cs  = Bna + (size_t)NCH * nb * DH;
    float* Ns  = Cs  + (size_t)NCH * nb * DH;

    transpose_w<<<2048, 256, 0, stream>>>(Wi, Wf, Wo, Wz, Wt);

    for (int b0 = 0; b0 < BB; b0 += nb) {
        const float* Xsrc = x   + (size_t)b0 * SS * DIN;
        float*       Ob   = out + (size_t)b0 * SS * DH;
        convert_x<<<nb * 1024, 256, 0, stream>>>(Xsrc, Xb);
        gemm_mfma<<<dim3(nb * SS / 128, 16), 256, 0, stream>>>(
            Xb, Wt, bi, bfv, bo, bz, Pi, Pf, Po, Pz);
        scan_carry<<<dim3(NCH / 4, nb), 256, 0, stream>>>(
            Pi, Pf, Pz, Aa, Bca, Bna, nb);
        scan_chunks<<<2 * nb, 256, 0, stream>>>(Aa, Bca, Bna, Cs, Ns, nb);
        scan_emit<<<dim3(NCH / 4, nb), 256, 0, stream>>>(
            Pi, Pf, Po, Pz, Cs, Ns, Ob, nb);
    }
}